// Round 1
// baseline (8809.648 us; speedup 1.0000x reference)
//
#include <hip/hip_runtime.h>
#include <hip/hip_bf16.h>
#include <cstddef>

// Problem constants
#define BB    256
#define TT    512
#define DIN   64
#define H1    256
#define INTER 128
#define STATE 256
#define MOTOR 64
#define DOUT  32
#define BT    (BB*TT)   // 131072

#define TOK   16        // tokens per MLP block
#define TOKP  20        // padded LDS stride (bank-conflict-free float4 reads)

__device__ __forceinline__ float tanh_fast(float x) {
    // tanh(x) = 1 - 2/(exp(2x)+1); exp overflow/underflow saturates correctly.
    float e = __expf(2.0f * x);
    return 1.0f - 2.0f / (e + 1.0f);
}

// ---------------------------------------------------------------------------
// One MLP layer on transposed LDS activations.
// inT:  LDS [K][TOKP]   (activation^T)
// outT: LDS [N][TOKP]
// W:    global [K][N] row-major, bias: [N]
// Thread micro-tile: 4 tokens x 4 cols; slots = N (threads >= N idle).
// NO internal barrier — caller must __syncthreads() after.
// ---------------------------------------------------------------------------
template<int K, int N, bool TANH>
__device__ __forceinline__ void layer_T(const float* __restrict__ W,
                                        const float* __restrict__ bias,
                                        const float* inT, float* outT) {
    const int tid = threadIdx.x;
    if (tid < N) {
        const int CG = N / 4;
        const int t0 = (tid / CG) * 4;
        const int n0 = (tid % CG) * 4;
        float4 bv = *(const float4*)(bias + n0);
        float acc[4][4];   // [token][col]
        #pragma unroll
        for (int j = 0; j < 4; ++j) {
            acc[j][0] = bv.x; acc[j][1] = bv.y; acc[j][2] = bv.z; acc[j][3] = bv.w;
        }
        #pragma unroll 4
        for (int k = 0; k < K; ++k) {
            float4 a = *(const float4*)(inT + k*TOKP + t0);
            float4 w = *(const float4*)(W + k*N + n0);
            acc[0][0] += a.x*w.x; acc[0][1] += a.x*w.y; acc[0][2] += a.x*w.z; acc[0][3] += a.x*w.w;
            acc[1][0] += a.y*w.x; acc[1][1] += a.y*w.y; acc[1][2] += a.y*w.z; acc[1][3] += a.y*w.w;
            acc[2][0] += a.z*w.x; acc[2][1] += a.z*w.y; acc[2][2] += a.z*w.z; acc[2][3] += a.z*w.w;
            acc[3][0] += a.w*w.x; acc[3][1] += a.w*w.y; acc[3][2] += a.w*w.z; acc[3][3] += a.w*w.w;
        }
        #pragma unroll
        for (int j = 0; j < 4; ++j) {
            #pragma unroll
            for (int i = 0; i < 4; ++i) {
                float v = acc[j][i];
                if (TANH) v = tanh_fast(v);
                outT[(n0 + i)*TOKP + (t0 + j)] = v;
            }
        }
    }
}

// Same micro-tile but writes ROW-major to global (used for the u projection).
template<int K, int N, bool TANH>
__device__ __forceinline__ void layer_G(const float* __restrict__ W,
                                        const float* __restrict__ bias,
                                        const float* inT,
                                        float* __restrict__ gout, int row0) {
    const int tid = threadIdx.x;
    if (tid < N) {
        const int CG = N / 4;
        const int t0 = (tid / CG) * 4;
        const int n0 = (tid % CG) * 4;
        float4 bv = *(const float4*)(bias + n0);
        float acc[4][4];
        #pragma unroll
        for (int j = 0; j < 4; ++j) {
            acc[j][0] = bv.x; acc[j][1] = bv.y; acc[j][2] = bv.z; acc[j][3] = bv.w;
        }
        #pragma unroll 4
        for (int k = 0; k < K; ++k) {
            float4 a = *(const float4*)(inT + k*TOKP + t0);
            float4 w = *(const float4*)(W + k*N + n0);
            acc[0][0] += a.x*w.x; acc[0][1] += a.x*w.y; acc[0][2] += a.x*w.z; acc[0][3] += a.x*w.w;
            acc[1][0] += a.y*w.x; acc[1][1] += a.y*w.y; acc[1][2] += a.y*w.z; acc[1][3] += a.y*w.w;
            acc[2][0] += a.z*w.x; acc[2][1] += a.z*w.y; acc[2][2] += a.z*w.z; acc[2][3] += a.z*w.w;
            acc[3][0] += a.w*w.x; acc[3][1] += a.w*w.y; acc[3][2] += a.w*w.z; acc[3][3] += a.w*w.w;
        }
        #pragma unroll
        for (int j = 0; j < 4; ++j) {
            float v0 = acc[j][0], v1 = acc[j][1], v2 = acc[j][2], v3 = acc[j][3];
            if (TANH) { v0 = tanh_fast(v0); v1 = tanh_fast(v1); v2 = tanh_fast(v2); v3 = tanh_fast(v3); }
            *(float4*)(gout + (size_t)(row0 + t0 + j)*N + n0) = make_float4(v0, v1, v2, v3);
        }
    }
}

// ---------------------------------------------------------------------------
// Weight transposes (once per launch): WhhT[n][j] = Whh[j][n]; WhoT[o][j] = Who[j][o]
// ---------------------------------------------------------------------------
__global__ __launch_bounds__(256) void prep_kernel(const float* __restrict__ Whh,
                                                   const float* __restrict__ Who,
                                                   float* __restrict__ WhhT,
                                                   float* __restrict__ WhoT) {
    int idx = blockIdx.x * 256 + threadIdx.x;
    if (idx < STATE*STATE) {
        int j = idx >> 8, n = idx & 255;
        WhhT[n*STATE + j] = Whh[j*STATE + n];
    } else {
        int idx2 = idx - STATE*STATE;
        if (idx2 < STATE*MOTOR) {
            int j = idx2 >> 6, o = idx2 & 63;
            WhoT[o*STATE + j] = Who[j*MOTOR + o];
        }
    }
}

// ---------------------------------------------------------------------------
// Fused encoder: x -> tanh(Wi1) -> tanh(Wi2) -> Wi3 -> (Wih + bh) = u
// ---------------------------------------------------------------------------
__global__ __launch_bounds__(256) void encoder_kernel(
    const float* __restrict__ x,
    const float* __restrict__ Wi1, const float* __restrict__ bi1,
    const float* __restrict__ Wi2, const float* __restrict__ bi2,
    const float* __restrict__ Wi3, const float* __restrict__ bi3,
    const float* __restrict__ Wih, const float* __restrict__ bh,
    float* __restrict__ u)
{
    __shared__ float bufX[DIN   * TOKP];
    __shared__ float bufA[H1    * TOKP];
    __shared__ float bufB[H1    * TOKP];
    __shared__ float bufE[INTER * TOKP];
    const int tid  = threadIdx.x;
    const int row0 = blockIdx.x * TOK;

    { // load x tile transposed: bufX[c][t]
        int t  = tid >> 4;
        int c0 = (tid & 15) * 4;
        float4 v = *(const float4*)(x + (size_t)(row0 + t)*DIN + c0);
        bufX[(c0+0)*TOKP + t] = v.x;
        bufX[(c0+1)*TOKP + t] = v.y;
        bufX[(c0+2)*TOKP + t] = v.z;
        bufX[(c0+3)*TOKP + t] = v.w;
    }
    __syncthreads();
    layer_T<DIN,  H1,    true >(Wi1, bi1, bufX, bufA);
    __syncthreads();
    layer_T<H1,   H1,    true >(Wi2, bi2, bufA, bufB);
    __syncthreads();
    layer_T<H1,   INTER, false>(Wi3, bi3, bufB, bufE);
    __syncthreads();
    layer_G<INTER, STATE, false>(Wih, bh, bufE, u, row0);
}

// ---------------------------------------------------------------------------
// RNN scan: 64 blocks x 4 samples, 512 threads (j-dim split in half per thread).
// h kept fp32 in LDS ([j][s] for the h-update, [s][j] copy for the motor GEMV).
// ---------------------------------------------------------------------------
__global__ __launch_bounds__(512) void rnn_kernel(
    const float* __restrict__ u,      // [B*T, STATE]
    const float* __restrict__ WhhT,   // [STATE][STATE]  (T of Whh)
    const float* __restrict__ WhoT,   // [MOTOR][STATE]  (T of Who)
    const float* __restrict__ bo,     // [MOTOR]
    float* __restrict__ m)            // [B*T, MOTOR]
{
    __shared__ float h4[STATE * 4];     // [j][s]
    __shared__ float hrow[4 * 260];     // [s][j] padded
    __shared__ float part[512 * 4];     // k-split partials
    __shared__ float mpart[512];

    const int tid   = threadIdx.x;
    const int b0    = blockIdx.x * 4;
    const int n     = tid & 255;
    const int jbase = (tid >> 8) * 128;
    const int o     = tid & 63;
    const int so    = (tid >> 6) & 3;

    if (tid < 256) *(float4*)(h4 + tid*4) = make_float4(0.f, 0.f, 0.f, 0.f);
    __syncthreads();

    for (int t = 0; t < TT; ++t) {
        // prefetch u for this (n, s=0..3) — hides global latency under the j-loop
        float up0 = 0.f, up1 = 0.f, up2 = 0.f, up3 = 0.f;
        if (tid < 256) {
            const float* ub = u + ((size_t)b0*TT + t)*STATE + n;
            up0 = ub[0];
            up1 = ub[(size_t)TT*STATE];
            up2 = ub[(size_t)2*TT*STATE];
            up3 = ub[(size_t)3*TT*STATE];
        }
        // h-phase: partial dot over j in [jbase, jbase+128)
        float a0 = 0.f, a1 = 0.f, a2 = 0.f, a3 = 0.f;
        {
            const float* wr = WhhT + n*STATE + jbase;
            const float* hp = h4 + jbase*4;
            #pragma unroll 4
            for (int jj = 0; jj < 128; jj += 4) {
                float4 w  = *(const float4*)(wr + jj);
                float4 hA = *(const float4*)(hp + jj*4);
                float4 hB = *(const float4*)(hp + jj*4 + 4);
                float4 hC = *(const float4*)(hp + jj*4 + 8);
                float4 hD = *(const float4*)(hp + jj*4 + 12);
                a0 += w.x*hA.x + w.y*hB.x + w.z*hC.x + w.w*hD.x;
                a1 += w.x*hA.y + w.y*hB.y + w.z*hC.y + w.w*hD.y;
                a2 += w.x*hA.z + w.y*hB.z + w.z*hC.z + w.w*hD.z;
                a3 += w.x*hA.w + w.y*hB.w + w.z*hC.w + w.w*hD.w;
            }
        }
        *(float4*)(part + tid*4) = make_float4(a0, a1, a2, a3);
        __syncthreads();

        if (tid < 256) {  // reduce halves + u + tanh, publish h_new
            float4 pA = *(const float4*)(part + tid*4);
            float4 pB = *(const float4*)(part + (tid + 256)*4);
            float h0 = tanh_fast(pA.x + pB.x + up0);
            float h1 = tanh_fast(pA.y + pB.y + up1);
            float h2 = tanh_fast(pA.z + pB.z + up2);
            float h3 = tanh_fast(pA.w + pB.w + up3);
            *(float4*)(h4 + tid*4) = make_float4(h0, h1, h2, h3);
            hrow[0*260 + tid] = h0;
            hrow[1*260 + tid] = h1;
            hrow[2*260 + tid] = h2;
            hrow[3*260 + tid] = h3;
        }
        __syncthreads();

        // m-phase: thread (o, s, jhalf) computes a 128-j partial of m[s][o]
        {
            const float* wp = WhoT + o*STATE + jbase;
            const float* hr = hrow + so*260 + jbase;
            float acc = 0.f;
            #pragma unroll 4
            for (int jj = 0; jj < 128; jj += 4) {
                float4 w  = *(const float4*)(wp + jj);
                float4 hv = *(const float4*)(hr + jj);
                acc += w.x*hv.x + w.y*hv.y + w.z*hv.z + w.w*hv.w;
            }
            mpart[tid] = acc;
        }
        __syncthreads();

        if (tid < 256) {
            float mv = mpart[tid] + mpart[tid + 256] + bo[o];
            m[((size_t)(b0 + so)*TT + t)*MOTOR + o] = mv;
        }
        // no extra barrier needed: next h-phase writes only part[] (read-complete),
        // and h4/hrow writes sit behind the next barrier.
    }
}

// ---------------------------------------------------------------------------
// Fused decoder: m -> tanh(Wo1) -> tanh(Wo2) -> Wo3 -> y
// ---------------------------------------------------------------------------
__global__ __launch_bounds__(256) void decoder_kernel(
    const float* __restrict__ m,
    const float* __restrict__ Wo1, const float* __restrict__ bo1,
    const float* __restrict__ Wo2, const float* __restrict__ bo2,
    const float* __restrict__ Wo3, const float* __restrict__ bo3,
    float* __restrict__ y)
{
    __shared__ float bufM[MOTOR * TOKP];
    __shared__ float bufA[H1    * TOKP];
    __shared__ float bufB[H1    * TOKP];
    const int tid  = threadIdx.x;
    const int row0 = blockIdx.x * TOK;

    { // load m tile transposed
        int t  = tid >> 4;
        int c0 = (tid & 15) * 4;
        float4 v = *(const float4*)(m + (size_t)(row0 + t)*MOTOR + c0);
        bufM[(c0+0)*TOKP + t] = v.x;
        bufM[(c0+1)*TOKP + t] = v.y;
        bufM[(c0+2)*TOKP + t] = v.z;
        bufM[(c0+3)*TOKP + t] = v.w;
    }
    __syncthreads();
    layer_T<MOTOR, H1, true>(Wo1, bo1, bufM, bufA);
    __syncthreads();
    layer_T<H1,    H1, true>(Wo2, bo2, bufA, bufB);
    __syncthreads();
    { // final layer: K=256, N=32; micro-tile 1 token x 2 cols (256 slots, all busy)
        int t  = tid >> 4;          // 0..15
        int n0 = (tid & 15) * 2;    // 0..30
        float acc0 = bo3[n0], acc1 = bo3[n0 + 1];
        #pragma unroll 4
        for (int k = 0; k < H1; ++k) {
            float  a = bufB[k*TOKP + t];
            float2 w = *(const float2*)(Wo3 + k*DOUT + n0);
            acc0 += a * w.x;
            acc1 += a * w.y;
        }
        *(float2*)(y + (size_t)(row0 + t)*DOUT + n0) = make_float2(acc0, acc1);
    }
}

// ---------------------------------------------------------------------------
extern "C" void kernel_launch(void* const* d_in, const int* in_sizes, int n_in,
                              void* d_out, int out_size, void* d_ws, size_t ws_size,
                              hipStream_t stream) {
    const float* x   = (const float*)d_in[0];
    const float* Wi1 = (const float*)d_in[1];
    const float* bi1 = (const float*)d_in[2];
    const float* Wi2 = (const float*)d_in[3];
    const float* bi2 = (const float*)d_in[4];
    const float* Wi3 = (const float*)d_in[5];
    const float* bi3 = (const float*)d_in[6];
    const float* Wih = (const float*)d_in[7];
    const float* Whh = (const float*)d_in[8];
    const float* bh  = (const float*)d_in[9];
    const float* Who = (const float*)d_in[10];
    const float* bo  = (const float*)d_in[11];
    const float* Wo1 = (const float*)d_in[12];
    const float* bo1 = (const float*)d_in[13];
    const float* Wo2 = (const float*)d_in[14];
    const float* bo2 = (const float*)d_in[15];
    const float* Wo3 = (const float*)d_in[16];
    const float* bo3 = (const float*)d_in[17];
    float* y = (float*)d_out;

    // workspace layout (floats): u[BT*STATE] | m[BT*MOTOR] | WhhT | WhoT  (~168 MB)
    float* u    = (float*)d_ws;
    float* mbuf = u    + (size_t)BT * STATE;
    float* WhhT = mbuf + (size_t)BT * MOTOR;
    float* WhoT = WhhT + (size_t)STATE * STATE;

    prep_kernel<<<(STATE*STATE + STATE*MOTOR + 255)/256, 256, 0, stream>>>(Whh, Who, WhhT, WhoT);
    encoder_kernel<<<BT/TOK, 256, 0, stream>>>(x, Wi1, bi1, Wi2, bi2, Wi3, bi3, Wih, bh, u);
    rnn_kernel<<<BB/4, 512, 0, stream>>>(u, WhhT, WhoT, bo, mbuf);
    decoder_kernel<<<BT/TOK, 256, 0, stream>>>(mbuf, Wo1, bo1, Wo2, bo2, Wo3, bo3, y);
}

// Round 2
// 1839.105 us; speedup vs baseline: 4.7902x; 4.7902x over previous
//
#include <hip/hip_runtime.h>
#include <hip/hip_bf16.h>
#include <cstddef>

// Problem constants
#define BB    256
#define TT    512
#define DIN   64
#define H1    256
#define INTER 128
#define STATE 256
#define MOTOR 64
#define DOUT  32
#define BT    (BB*TT)   // 131072

#define TOK   16        // tokens per MLP block
#define TOKP  20        // padded LDS stride (bank-conflict-free float4 reads)

__device__ __forceinline__ float tanh_fast(float x) {
    // tanh(x) = 1 - 2/(exp(2x)+1); exp overflow/underflow saturates correctly.
    float e = __expf(2.0f * x);
    return 1.0f - 2.0f / (e + 1.0f);
}

// ---------------------------------------------------------------------------
// One MLP layer on transposed LDS activations.
// inT:  LDS [K][TOKP]   (activation^T)
// outT: LDS [N][TOKP]
// W:    global [K][N] row-major, bias: [N]
// Thread micro-tile: 4 tokens x 4 cols; slots = N (threads >= N idle).
// NO internal barrier — caller must __syncthreads() after.
// ---------------------------------------------------------------------------
template<int K, int N, bool TANH>
__device__ __forceinline__ void layer_T(const float* __restrict__ W,
                                        const float* __restrict__ bias,
                                        const float* inT, float* outT) {
    const int tid = threadIdx.x;
    if (tid < N) {
        const int CG = N / 4;
        const int t0 = (tid / CG) * 4;
        const int n0 = (tid % CG) * 4;
        float4 bv = *(const float4*)(bias + n0);
        float acc[4][4];   // [token][col]
        #pragma unroll
        for (int j = 0; j < 4; ++j) {
            acc[j][0] = bv.x; acc[j][1] = bv.y; acc[j][2] = bv.z; acc[j][3] = bv.w;
        }
        #pragma unroll 4
        for (int k = 0; k < K; ++k) {
            float4 a = *(const float4*)(inT + k*TOKP + t0);
            float4 w = *(const float4*)(W + k*N + n0);
            acc[0][0] += a.x*w.x; acc[0][1] += a.x*w.y; acc[0][2] += a.x*w.z; acc[0][3] += a.x*w.w;
            acc[1][0] += a.y*w.x; acc[1][1] += a.y*w.y; acc[1][2] += a.y*w.z; acc[1][3] += a.y*w.w;
            acc[2][0] += a.z*w.x; acc[2][1] += a.z*w.y; acc[2][2] += a.z*w.z; acc[2][3] += a.z*w.w;
            acc[3][0] += a.w*w.x; acc[3][1] += a.w*w.y; acc[3][2] += a.w*w.z; acc[3][3] += a.w*w.w;
        }
        #pragma unroll
        for (int j = 0; j < 4; ++j) {
            #pragma unroll
            for (int i = 0; i < 4; ++i) {
                float v = acc[j][i];
                if (TANH) v = tanh_fast(v);
                outT[(n0 + i)*TOKP + (t0 + j)] = v;
            }
        }
    }
}

// Same micro-tile but writes ROW-major to global (used for the u projection).
template<int K, int N, bool TANH>
__device__ __forceinline__ void layer_G(const float* __restrict__ W,
                                        const float* __restrict__ bias,
                                        const float* inT,
                                        float* __restrict__ gout, int row0) {
    const int tid = threadIdx.x;
    if (tid < N) {
        const int CG = N / 4;
        const int t0 = (tid / CG) * 4;
        const int n0 = (tid % CG) * 4;
        float4 bv = *(const float4*)(bias + n0);
        float acc[4][4];
        #pragma unroll
        for (int j = 0; j < 4; ++j) {
            acc[j][0] = bv.x; acc[j][1] = bv.y; acc[j][2] = bv.z; acc[j][3] = bv.w;
        }
        #pragma unroll 4
        for (int k = 0; k < K; ++k) {
            float4 a = *(const float4*)(inT + k*TOKP + t0);
            float4 w = *(const float4*)(W + k*N + n0);
            acc[0][0] += a.x*w.x; acc[0][1] += a.x*w.y; acc[0][2] += a.x*w.z; acc[0][3] += a.x*w.w;
            acc[1][0] += a.y*w.x; acc[1][1] += a.y*w.y; acc[1][2] += a.y*w.z; acc[1][3] += a.y*w.w;
            acc[2][0] += a.z*w.x; acc[2][1] += a.z*w.y; acc[2][2] += a.z*w.z; acc[2][3] += a.z*w.w;
            acc[3][0] += a.w*w.x; acc[3][1] += a.w*w.y; acc[3][2] += a.w*w.z; acc[3][3] += a.w*w.w;
        }
        #pragma unroll
        for (int j = 0; j < 4; ++j) {
            float v0 = acc[j][0], v1 = acc[j][1], v2 = acc[j][2], v3 = acc[j][3];
            if (TANH) { v0 = tanh_fast(v0); v1 = tanh_fast(v1); v2 = tanh_fast(v2); v3 = tanh_fast(v3); }
            *(float4*)(gout + (size_t)(row0 + t0 + j)*N + n0) = make_float4(v0, v1, v2, v3);
        }
    }
}

// ---------------------------------------------------------------------------
// Weight transposes (once per launch): WhhT[n][j] = Whh[j][n]; WhoT[o][j] = Who[j][o]
// ---------------------------------------------------------------------------
__global__ __launch_bounds__(256) void prep_kernel(const float* __restrict__ Whh,
                                                   const float* __restrict__ Who,
                                                   float* __restrict__ WhhT,
                                                   float* __restrict__ WhoT) {
    int idx = blockIdx.x * 256 + threadIdx.x;
    if (idx < STATE*STATE) {
        int j = idx >> 8, n = idx & 255;
        WhhT[n*STATE + j] = Whh[j*STATE + n];
    } else {
        int idx2 = idx - STATE*STATE;
        if (idx2 < STATE*MOTOR) {
            int j = idx2 >> 6, o = idx2 & 63;
            WhoT[o*STATE + j] = Who[j*MOTOR + o];
        }
    }
}

// ---------------------------------------------------------------------------
// Fused encoder: x -> tanh(Wi1) -> tanh(Wi2) -> Wi3 -> (Wih + bh) = u
// ---------------------------------------------------------------------------
__global__ __launch_bounds__(256) void encoder_kernel(
    const float* __restrict__ x,
    const float* __restrict__ Wi1, const float* __restrict__ bi1,
    const float* __restrict__ Wi2, const float* __restrict__ bi2,
    const float* __restrict__ Wi3, const float* __restrict__ bi3,
    const float* __restrict__ Wih, const float* __restrict__ bh,
    float* __restrict__ u)
{
    __shared__ float bufX[DIN   * TOKP];
    __shared__ float bufA[H1    * TOKP];
    __shared__ float bufB[H1    * TOKP];
    __shared__ float bufE[INTER * TOKP];
    const int tid  = threadIdx.x;
    const int row0 = blockIdx.x * TOK;

    { // load x tile transposed: bufX[c][t]
        int t  = tid >> 4;
        int c0 = (tid & 15) * 4;
        float4 v = *(const float4*)(x + (size_t)(row0 + t)*DIN + c0);
        bufX[(c0+0)*TOKP + t] = v.x;
        bufX[(c0+1)*TOKP + t] = v.y;
        bufX[(c0+2)*TOKP + t] = v.z;
        bufX[(c0+3)*TOKP + t] = v.w;
    }
    __syncthreads();
    layer_T<DIN,  H1,    true >(Wi1, bi1, bufX, bufA);
    __syncthreads();
    layer_T<H1,   H1,    true >(Wi2, bi2, bufA, bufB);
    __syncthreads();
    layer_T<H1,   INTER, false>(Wi3, bi3, bufB, bufE);
    __syncthreads();
    layer_G<INTER, STATE, false>(Wih, bh, bufE, u, row0);
}

// ---------------------------------------------------------------------------
// RNN scan, v2: 256 blocks x 1 sample, 512 threads.
// Whh^T and Who^T slices live in REGISTERS (loaded once); h lives in LDS
// (256 floats), read via uniform-address (broadcast) ds_read_b128.
// Thread (n = tid&255, jhalf = tid>>8) computes half the dot for h_new[n].
// Thread (o = tid&63,  q     = tid>>6) computes 1/8 of the dot for m[o].
// ---------------------------------------------------------------------------
__global__ __launch_bounds__(512, 2) void rnn_kernel(
    const float* __restrict__ u,      // [B*T, STATE]
    const float* __restrict__ WhhT,   // [STATE][STATE]  (T of Whh)
    const float* __restrict__ WhoT,   // [MOTOR][STATE]  (T of Who)
    const float* __restrict__ bo,     // [MOTOR]
    float* __restrict__ m)            // [B*T, MOTOR]
{
    __shared__ float hbuf[STATE + 8];   // h (fp32)
    __shared__ float part[512];         // h-phase k-split partials
    __shared__ float mp[512 + 8];       // m-phase partials

    const int tid   = threadIdx.x;
    const int b     = blockIdx.x;
    const int n     = tid & 255;
    const int jbase = (tid >> 8) * 128;   // 0 or 128
    const int o     = tid & 63;
    const int q     = tid >> 6;           // 0..7

    // --- weights -> registers (once) ---
    float4 wh[32];
    {
        const float* wr = WhhT + n*STATE + jbase;
        #pragma unroll
        for (int i = 0; i < 32; ++i) wh[i] = *(const float4*)(wr + 4*i);
    }
    float4 wo[8];
    {
        const float* wr = WhoT + o*STATE + q*32;
        #pragma unroll
        for (int i = 0; i < 8; ++i) wo[i] = *(const float4*)(wr + 4*i);
    }
    const float bov = bo[o];

    if (tid < 256) hbuf[tid] = 0.0f;

    const float* ubase = u + (size_t)b*TT*STATE + n;   // stride STATE per t
    float*       mrow  = m + (size_t)b*TT*MOTOR + o;   // stride MOTOR per t

    float up = (tid < 256) ? ubase[0] : 0.0f;          // u for t=0
    __syncthreads();

    for (int t = 0; t < TT; ++t) {
        // prefetch u for t+1 (consumed after next barrier -> latency hidden)
        float upn = 0.0f;
        if (tid < 256 && t + 1 < TT) upn = ubase[(size_t)(t+1)*STATE];

        // --- h-phase: partial dot over my 128-j slice, weights from VGPRs ---
        float ax = 0.f, ay = 0.f, az = 0.f, aw = 0.f;
        {
            const float* hp = hbuf + jbase;
            #pragma unroll
            for (int i = 0; i < 32; ++i) {
                float4 hv = *(const float4*)(hp + 4*i);   // uniform addr: broadcast
                ax = fmaf(wh[i].x, hv.x, ax);
                ay = fmaf(wh[i].y, hv.y, ay);
                az = fmaf(wh[i].z, hv.z, az);
                aw = fmaf(wh[i].w, hv.w, aw);
            }
        }
        part[tid] = (ax + ay) + (az + aw);
        __syncthreads();

        // --- reduce halves + u + tanh, publish h_new ---
        if (tid < 256) {
            hbuf[tid] = tanh_fast(part[tid] + part[tid + 256] + up);
        }
        __syncthreads();

        // --- m-phase: 1/8 of dot for m[o], weights from VGPRs ---
        {
            const float* hq = hbuf + q*32;
            float bx = 0.f, by = 0.f, bz = 0.f, bw = 0.f;
            #pragma unroll
            for (int i = 0; i < 8; ++i) {
                float4 hv = *(const float4*)(hq + 4*i);   // uniform addr: broadcast
                bx = fmaf(wo[i].x, hv.x, bx);
                by = fmaf(wo[i].y, hv.y, by);
                bz = fmaf(wo[i].z, hv.z, bz);
                bw = fmaf(wo[i].w, hv.w, bw);
            }
            mp[tid] = (bx + by) + (bz + bw);
        }
        __syncthreads();

        if (tid < 64) {
            float mv = bov;
            #pragma unroll
            for (int qq = 0; qq < 8; ++qq) mv += mp[o + 64*qq];
            mrow[(size_t)t*MOTOR] = mv;
        }
        up = upn;
        // next h-phase reads hbuf (stable until next publish, which is behind
        // a barrier) and writes part[] (all reads completed before barrier 2).
    }
}

// ---------------------------------------------------------------------------
// Fused decoder: m -> tanh(Wo1) -> tanh(Wo2) -> Wo3 -> y
// ---------------------------------------------------------------------------
__global__ __launch_bounds__(256) void decoder_kernel(
    const float* __restrict__ m,
    const float* __restrict__ Wo1, const float* __restrict__ bo1,
    const float* __restrict__ Wo2, const float* __restrict__ bo2,
    const float* __restrict__ Wo3, const float* __restrict__ bo3,
    float* __restrict__ y)
{
    __shared__ float bufM[MOTOR * TOKP];
    __shared__ float bufA[H1    * TOKP];
    __shared__ float bufB[H1    * TOKP];
    const int tid  = threadIdx.x;
    const int row0 = blockIdx.x * TOK;

    { // load m tile transposed
        int t  = tid >> 4;
        int c0 = (tid & 15) * 4;
        float4 v = *(const float4*)(m + (size_t)(row0 + t)*MOTOR + c0);
        bufM[(c0+0)*TOKP + t] = v.x;
        bufM[(c0+1)*TOKP + t] = v.y;
        bufM[(c0+2)*TOKP + t] = v.z;
        bufM[(c0+3)*TOKP + t] = v.w;
    }
    __syncthreads();
    layer_T<MOTOR, H1, true>(Wo1, bo1, bufM, bufA);
    __syncthreads();
    layer_T<H1,    H1, true>(Wo2, bo2, bufA, bufB);
    __syncthreads();
    { // final layer: K=256, N=32; micro-tile 1 token x 2 cols (256 slots, all busy)
        int t  = tid >> 4;          // 0..15
        int n0 = (tid & 15) * 2;    // 0..30
        float acc0 = bo3[n0], acc1 = bo3[n0 + 1];
        #pragma unroll 4
        for (int k = 0; k < H1; ++k) {
            float  a = bufB[k*TOKP + t];
            float2 w = *(const float2*)(Wo3 + k*DOUT + n0);
            acc0 += a * w.x;
            acc1 += a * w.y;
        }
        *(float2*)(y + (size_t)(row0 + t)*DOUT + n0) = make_float2(acc0, acc1);
    }
}

// ---------------------------------------------------------------------------
extern "C" void kernel_launch(void* const* d_in, const int* in_sizes, int n_in,
                              void* d_out, int out_size, void* d_ws, size_t ws_size,
                              hipStream_t stream) {
    const float* x   = (const float*)d_in[0];
    const float* Wi1 = (const float*)d_in[1];
    const float* bi1 = (const float*)d_in[2];
    const float* Wi2 = (const float*)d_in[3];
    const float* bi2 = (const float*)d_in[4];
    const float* Wi3 = (const float*)d_in[5];
    const float* bi3 = (const float*)d_in[6];
    const float* Wih = (const float*)d_in[7];
    const float* Whh = (const float*)d_in[8];
    const float* bh  = (const float*)d_in[9];
    const float* Who = (const float*)d_in[10];
    const float* bo  = (const float*)d_in[11];
    const float* Wo1 = (const float*)d_in[12];
    const float* bo1 = (const float*)d_in[13];
    const float* Wo2 = (const float*)d_in[14];
    const float* bo2 = (const float*)d_in[15];
    const float* Wo3 = (const float*)d_in[16];
    const float* bo3 = (const float*)d_in[17];
    float* y = (float*)d_out;

    // workspace layout (floats): u[BT*STATE] | m[BT*MOTOR] | WhhT | WhoT  (~168 MB)
    float* u    = (float*)d_ws;
    float* mbuf = u    + (size_t)BT * STATE;
    float* WhhT = mbuf + (size_t)BT * MOTOR;
    float* WhoT = WhhT + (size_t)STATE * STATE;

    prep_kernel<<<(STATE*STATE + STATE*MOTOR + 255)/256, 256, 0, stream>>>(Whh, Who, WhhT, WhoT);
    encoder_kernel<<<BT/TOK, 256, 0, stream>>>(x, Wi1, bi1, Wi2, bi2, Wi3, bi3, Wih, bh, u);
    rnn_kernel<<<BB, 512, 0, stream>>>(u, WhhT, WhoT, bo, mbuf);
    decoder_kernel<<<BT/TOK, 256, 0, stream>>>(mbuf, Wo1, bo1, Wo2, bo2, Wo3, bo3, y);
}

// Round 3
// 1008.294 us; speedup vs baseline: 8.7372x; 1.8240x over previous
//
#include <hip/hip_runtime.h>
#include <hip/hip_bf16.h>
#include <cstddef>

// Problem constants
#define BB    256
#define TT    512
#define DIN   64
#define H1    256
#define INTER 128
#define STATE 256
#define MOTOR 64
#define DOUT  32
#define BT    (BB*TT)   // 131072

typedef unsigned int u32;
typedef short short8 __attribute__((ext_vector_type(8)));
typedef float f32x4  __attribute__((ext_vector_type(4)));

// Packed-weight (hi/lo bf16 in one u32) fragment-order offsets, in u32 elems
#define OFF_I1 0         // Wi1: 64x256   -> 16384
#define OFF_I2 16384     // Wi2: 256x256  -> 65536
#define OFF_I3 81920     // Wi3: 256x128  -> 32768
#define OFF_IH 114688    // Wih: 128x256  -> 32768
#define OFF_O1 147456    // Wo1: 64x256   -> 16384
#define OFF_O2 163840    // Wo2: 256x256  -> 65536
#define OFF_O3 229376    // Wo3: 256x32   -> 8192
#define BPK_TOTAL 237568

__device__ __forceinline__ float tanh_fast(float x) {
    float e = __expf(2.0f * x);
    return 1.0f - 2.0f / (e + 1.0f);
}

__device__ __forceinline__ u32 f2u(float f){ union{float f; u32 u;} v; v.f=f; return v.u; }
__device__ __forceinline__ float u2f(u32 u){ union{u32 u; float f;} v; v.u=u; return v.f; }

// fp32 -> packed (hi bf16 in [15:0], residual-lo bf16 in [31:16]), RNE both.
__device__ __forceinline__ u32 packhl(float x) {
    u32 b  = f2u(x);
    u32 hi = (b + 0x7fffu + ((b >> 16) & 1u)) >> 16;
    float lo = x - u2f(hi << 16);
    u32 bl = f2u(lo);
    u32 l16 = (bl + 0x7fffu + ((bl >> 16) & 1u)) >> 16;
    return (hi & 0xffffu) | (l16 << 16);
}

// 8 packed u32 -> hi-frag / lo-frag (each 8 bf16 as short8)
__device__ __forceinline__ void unpack8(uint4 w0, uint4 w1, short8& hi, short8& lo) {
    union { u32 u[4]; short8 s; } H, L;
    H.u[0] = __builtin_amdgcn_perm(w0.y, w0.x, 0x05040100u);
    L.u[0] = __builtin_amdgcn_perm(w0.y, w0.x, 0x07060302u);
    H.u[1] = __builtin_amdgcn_perm(w0.w, w0.z, 0x05040100u);
    L.u[1] = __builtin_amdgcn_perm(w0.w, w0.z, 0x07060302u);
    H.u[2] = __builtin_amdgcn_perm(w1.y, w1.x, 0x05040100u);
    L.u[2] = __builtin_amdgcn_perm(w1.y, w1.x, 0x07060302u);
    H.u[3] = __builtin_amdgcn_perm(w1.w, w1.z, 0x05040100u);
    L.u[3] = __builtin_amdgcn_perm(w1.w, w1.z, 0x07060302u);
    hi = H.s; lo = L.s;
}

// LDS activation addressing: [64 rows][256 words], XOR-swizzled in 16B units.
__device__ __forceinline__ int swz(int row, int col) {
    return row * 256 + (col ^ ((row & 7) << 2));
}

// ---------------------------------------------------------------------------
// One MFMA MLP layer over a 64-token tile held in LDS (packed hi/lo u32).
//   K: input features, N: output features (N/16 col-frags).
//   Wave wv owns col-frags [wv*NFW, wv*NFW+NFW) and ALL 4 row-frags.
//   Split-bf16: D += Ahi*Bhi + Ahi*Blo + Alo*Bhi  (~fp32 accuracy).
//   TOGLOBAL: write fp32 to gout[row*N + col]; else pack into outB.
// Caller must __syncthreads() around calls.
// ---------------------------------------------------------------------------
template<int K, int N, bool TANH, bool TOGLOBAL>
__device__ __forceinline__ void mfma_layer(
    const u32* __restrict__ Bpk, const float* __restrict__ bias,
    const u32* inB, u32* outB, float* __restrict__ gout,
    int lane, int wv)
{
    constexpr int NF  = N / 16;
    constexpr int NFW = (NF >= 4) ? NF / 4 : 1;
    constexpr int KC  = K / 32;
    const int q = lane >> 4, c = lane & 15;
    const int nf0 = wv * NFW;
    if (nf0 >= NF) return;   // small-N layers idle the upper waves

    f32x4 acc[4][NFW];
    #pragma unroll
    for (int nf = 0; nf < NFW; ++nf) {
        float bv = bias[(nf0 + nf) * 16 + c];
        #pragma unroll
        for (int rf = 0; rf < 4; ++rf) acc[rf][nf] = (f32x4){bv, bv, bv, bv};
    }

    #pragma unroll 2
    for (int kc = 0; kc < KC; ++kc) {
        // A fragments for the 4 row-frags (from LDS, swizzled)
        short8 ahi[4], alo[4];
        #pragma unroll
        for (int rf = 0; rf < 4; ++rf) {
            int row = rf * 16 + c;
            int kb  = kc * 32 + q * 8;
            int m4  = (row & 7) << 2;
            uint4 w0 = *(const uint4*)(inB + row * 256 + ( kb      ^ m4));
            uint4 w1 = *(const uint4*)(inB + row * 256 + ((kb + 4) ^ m4));
            unpack8(w0, w1, ahi[rf], alo[rf]);
        }
        #pragma unroll
        for (int nf = 0; nf < NFW; ++nf) {
            const u32* bp = Bpk + (((size_t)(kc * NF + nf0 + nf) * 64 + lane) * 8);
            uint4 b0 = *(const uint4*)bp;
            uint4 b1 = *(const uint4*)(bp + 4);
            short8 bhi, blo; unpack8(b0, b1, bhi, blo);
            #pragma unroll
            for (int rf = 0; rf < 4; ++rf) {
                acc[rf][nf] = __builtin_amdgcn_mfma_f32_16x16x32_bf16(ahi[rf], bhi, acc[rf][nf], 0, 0, 0);
                acc[rf][nf] = __builtin_amdgcn_mfma_f32_16x16x32_bf16(ahi[rf], blo, acc[rf][nf], 0, 0, 0);
                acc[rf][nf] = __builtin_amdgcn_mfma_f32_16x16x32_bf16(alo[rf], bhi, acc[rf][nf], 0, 0, 0);
            }
        }
    }

    // epilogue: D mapping is row = rf*16 + q*4 + r, col = (nf0+nf)*16 + c
    #pragma unroll
    for (int rf = 0; rf < 4; ++rf) {
        #pragma unroll
        for (int nf = 0; nf < NFW; ++nf) {
            #pragma unroll
            for (int r = 0; r < 4; ++r) {
                float v = acc[rf][nf][r];
                if (TANH) v = tanh_fast(v);
                int row = rf * 16 + q * 4 + r;
                int col = (nf0 + nf) * 16 + c;
                if (TOGLOBAL) gout[(size_t)row * N + col] = v;
                else          outB[swz(row, col)] = packhl(v);
            }
        }
    }
}

// Stage a [64 tokens][64 cols] fp32 global tile into packed LDS (cols 0..63).
__device__ __forceinline__ void stage64(const float* __restrict__ src, u32* dst, int tid) {
    int tt = tid >> 4;
    int c4 = (tid & 15) * 4;
    #pragma unroll
    for (int i = 0; i < 4; ++i) {
        int tok = tt + 16 * i;
        float4 v = *(const float4*)(src + (size_t)tok * 64 + c4);
        uint4 p;
        p.x = packhl(v.x); p.y = packhl(v.y); p.z = packhl(v.z); p.w = packhl(v.w);
        *(uint4*)(dst + swz(tok, c4)) = p;
    }
}

// ---------------------------------------------------------------------------
// prep: pack all MLP weights into MFMA-fragment order (hi/lo u32), and build
// WhhT / WhoT for the RNN.  Frag order: idx = ((kc*NF + nf)*64 + lane)*8 + e,
// element = W[kc*32 + (lane>>4)*8 + e][nf*16 + (lane&15)].
// ---------------------------------------------------------------------------
__global__ __launch_bounds__(256) void prep_kernel(
    const float* __restrict__ Wi1, const float* __restrict__ Wi2,
    const float* __restrict__ Wi3, const float* __restrict__ Wih,
    const float* __restrict__ Wo1, const float* __restrict__ Wo2,
    const float* __restrict__ Wo3,
    const float* __restrict__ Whh, const float* __restrict__ Who,
    u32* __restrict__ Bpk, float* __restrict__ WhhT, float* __restrict__ WhoT)
{
    int idx = blockIdx.x * 256 + threadIdx.x;
    if (idx < BPK_TOTAL) {
        const float* W; int NF; int i = idx;
        if      (i < OFF_I2) { W = Wi1; NF = 16; i -= OFF_I1; }
        else if (i < OFF_I3) { W = Wi2; NF = 16; i -= OFF_I2; }
        else if (i < OFF_IH) { W = Wi3; NF = 8;  i -= OFF_I3; }
        else if (i < OFF_O1) { W = Wih; NF = 16; i -= OFF_IH; }
        else if (i < OFF_O2) { W = Wo1; NF = 16; i -= OFF_O1; }
        else if (i < OFF_O3) { W = Wo2; NF = 16; i -= OFF_O2; }
        else                 { W = Wo3; NF = 2;  i -= OFF_O3; }
        int e = i & 7, l = (i >> 3) & 63, t = i >> 9;
        int nf = t % NF, kc = t / NF;
        int k = kc * 32 + ((l >> 4) * 8) + e;
        int n = nf * 16 + (l & 15);
        Bpk[idx] = packhl(W[(size_t)k * (NF * 16) + n]);
    } else if (idx < BPK_TOTAL + STATE*STATE) {
        int i = idx - BPK_TOTAL; int j = i >> 8, n = i & 255;
        WhhT[n * STATE + j] = Whh[j * STATE + n];
    } else if (idx < BPK_TOTAL + STATE*STATE + STATE*MOTOR) {
        int i = idx - BPK_TOTAL - STATE*STATE; int j = i >> 6, o = i & 63;
        WhoT[o * STATE + j] = Who[j * MOTOR + o];
    }
}

// ---------------------------------------------------------------------------
// MFMA encoder: x -> tanh(Wi1) -> tanh(Wi2) -> Wi3 -> (Wih + bh) = u
// 64 tokens/block, 4 waves, ping-pong packed LDS (2 x 64 KiB).
// ---------------------------------------------------------------------------
__global__ __launch_bounds__(256, 1) void encoder_mfma(
    const float* __restrict__ x, const u32* __restrict__ Bpk,
    const float* __restrict__ bi1, const float* __restrict__ bi2,
    const float* __restrict__ bi3, const float* __restrict__ bh,
    float* __restrict__ u)
{
    __shared__ u32 buf0[64 * 256];
    __shared__ u32 buf1[64 * 256];
    const int tid = threadIdx.x, lane = tid & 63, wv = tid >> 6;
    const size_t row0 = (size_t)blockIdx.x * 64;

    stage64(x + row0 * DIN, buf0, tid);
    __syncthreads();
    mfma_layer<DIN,  H1,    true,  false>(Bpk + OFF_I1, bi1, buf0, buf1, nullptr, lane, wv);
    __syncthreads();
    mfma_layer<H1,   H1,    true,  false>(Bpk + OFF_I2, bi2, buf1, buf0, nullptr, lane, wv);
    __syncthreads();
    mfma_layer<H1,   INTER, false, false>(Bpk + OFF_I3, bi3, buf0, buf1, nullptr, lane, wv);
    __syncthreads();
    mfma_layer<INTER,STATE, false, true >(Bpk + OFF_IH, bh,  buf1, nullptr, u + row0 * STATE, lane, wv);
}

// ---------------------------------------------------------------------------
// MFMA decoder: m -> tanh(Wo1) -> tanh(Wo2) -> Wo3 -> y
// ---------------------------------------------------------------------------
__global__ __launch_bounds__(256, 1) void decoder_mfma(
    const float* __restrict__ m, const u32* __restrict__ Bpk,
    const float* __restrict__ bo1, const float* __restrict__ bo2,
    const float* __restrict__ bo3,
    float* __restrict__ y)
{
    __shared__ u32 buf0[64 * 256];
    __shared__ u32 buf1[64 * 256];
    const int tid = threadIdx.x, lane = tid & 63, wv = tid >> 6;
    const size_t row0 = (size_t)blockIdx.x * 64;

    stage64(m + row0 * MOTOR, buf0, tid);
    __syncthreads();
    mfma_layer<MOTOR, H1,   true,  false>(Bpk + OFF_O1, bo1, buf0, buf1, nullptr, lane, wv);
    __syncthreads();
    mfma_layer<H1,    H1,   true,  false>(Bpk + OFF_O2, bo2, buf1, buf0, nullptr, lane, wv);
    __syncthreads();
    mfma_layer<H1,    DOUT, false, true >(Bpk + OFF_O3, bo3, buf0, nullptr, y + row0 * DOUT, lane, wv);
}

// ---------------------------------------------------------------------------
// RNN scan (unchanged from round 2): 256 blocks x 1 sample, 512 threads.
// Whh^T / Who^T slices in registers; h broadcast from LDS.
// ---------------------------------------------------------------------------
__global__ __launch_bounds__(512, 2) void rnn_kernel(
    const float* __restrict__ u,      // [B*T, STATE]
    const float* __restrict__ WhhT,   // [STATE][STATE]
    const float* __restrict__ WhoT,   // [MOTOR][STATE]
    const float* __restrict__ bo,
    float* __restrict__ m)            // [B*T, MOTOR]
{
    __shared__ float hbuf[STATE + 8];
    __shared__ float part[512];
    __shared__ float mp[512 + 8];

    const int tid   = threadIdx.x;
    const int b     = blockIdx.x;
    const int n     = tid & 255;
    const int jbase = (tid >> 8) * 128;
    const int o     = tid & 63;
    const int q     = tid >> 6;

    float4 wh[32];
    {
        const float* wr = WhhT + n*STATE + jbase;
        #pragma unroll
        for (int i = 0; i < 32; ++i) wh[i] = *(const float4*)(wr + 4*i);
    }
    float4 wo[8];
    {
        const float* wr = WhoT + o*STATE + q*32;
        #pragma unroll
        for (int i = 0; i < 8; ++i) wo[i] = *(const float4*)(wr + 4*i);
    }
    const float bov = bo[o];

    if (tid < 256) hbuf[tid] = 0.0f;

    const float* ubase = u + (size_t)b*TT*STATE + n;
    float*       mrow  = m + (size_t)b*TT*MOTOR + o;

    float up = (tid < 256) ? ubase[0] : 0.0f;
    __syncthreads();

    for (int t = 0; t < TT; ++t) {
        float upn = 0.0f;
        if (tid < 256 && t + 1 < TT) upn = ubase[(size_t)(t+1)*STATE];

        float ax = 0.f, ay = 0.f, az = 0.f, aw = 0.f;
        {
            const float* hp = hbuf + jbase;
            #pragma unroll
            for (int i = 0; i < 32; ++i) {
                float4 hv = *(const float4*)(hp + 4*i);
                ax = fmaf(wh[i].x, hv.x, ax);
                ay = fmaf(wh[i].y, hv.y, ay);
                az = fmaf(wh[i].z, hv.z, az);
                aw = fmaf(wh[i].w, hv.w, aw);
            }
        }
        part[tid] = (ax + ay) + (az + aw);
        __syncthreads();

        if (tid < 256) {
            hbuf[tid] = tanh_fast(part[tid] + part[tid + 256] + up);
        }
        __syncthreads();

        {
            const float* hq = hbuf + q*32;
            float bx = 0.f, by = 0.f, bz = 0.f, bw = 0.f;
            #pragma unroll
            for (int i = 0; i < 8; ++i) {
                float4 hv = *(const float4*)(hq + 4*i);
                bx = fmaf(wo[i].x, hv.x, bx);
                by = fmaf(wo[i].y, hv.y, by);
                bz = fmaf(wo[i].z, hv.z, bz);
                bw = fmaf(wo[i].w, hv.w, bw);
            }
            mp[tid] = (bx + by) + (bz + bw);
        }
        __syncthreads();

        if (tid < 64) {
            float mv = bov;
            #pragma unroll
            for (int qq = 0; qq < 8; ++qq) mv += mp[o + 64*qq];
            mrow[(size_t)t*MOTOR] = mv;
        }
        up = upn;
    }
}

// ---------------------------------------------------------------------------
extern "C" void kernel_launch(void* const* d_in, const int* in_sizes, int n_in,
                              void* d_out, int out_size, void* d_ws, size_t ws_size,
                              hipStream_t stream) {
    const float* x   = (const float*)d_in[0];
    const float* Wi1 = (const float*)d_in[1];
    const float* bi1 = (const float*)d_in[2];
    const float* Wi2 = (const float*)d_in[3];
    const float* bi2 = (const float*)d_in[4];
    const float* Wi3 = (const float*)d_in[5];
    const float* bi3 = (const float*)d_in[6];
    const float* Wih = (const float*)d_in[7];
    const float* Whh = (const float*)d_in[8];
    const float* bh  = (const float*)d_in[9];
    const float* Who = (const float*)d_in[10];
    const float* bo  = (const float*)d_in[11];
    const float* Wo1 = (const float*)d_in[12];
    const float* bo1 = (const float*)d_in[13];
    const float* Wo2 = (const float*)d_in[14];
    const float* bo2 = (const float*)d_in[15];
    const float* Wo3 = (const float*)d_in[16];
    const float* bo3 = (const float*)d_in[17];
    float* y = (float*)d_out;

    // workspace (floats): u | mbuf | WhhT | WhoT | Bpk(u32)
    float* u    = (float*)d_ws;
    float* mbuf = u    + (size_t)BT * STATE;
    float* WhhT = mbuf + (size_t)BT * MOTOR;
    float* WhoT = WhhT + (size_t)STATE * STATE;
    u32*   Bpk  = (u32*)(WhoT + (size_t)STATE * MOTOR);

    int prep_items = BPK_TOTAL + STATE*STATE + STATE*MOTOR;
    prep_kernel<<<(prep_items + 255)/256, 256, 0, stream>>>(
        Wi1, Wi2, Wi3, Wih, Wo1, Wo2, Wo3, Whh, Who, Bpk, WhhT, WhoT);
    encoder_mfma<<<BT/64, 256, 0, stream>>>(x, Bpk, bi1, bi2, bi3, bh, u);
    rnn_kernel<<<BB, 512, 0, stream>>>(u, WhhT, WhoT, bo, mbuf);
    decoder_mfma<<<BT/64, 256, 0, stream>>>(mbuf, Bpk, bo1, bo2, bo3, y);
}